// Round 14
// baseline (745.552 us; speedup 1.0000x reference)
//

#include <hip/hip_runtime.h>
#include <hip/hip_bf16.h>

// Round 14 (base 741.3us):
//  - k_scatter: only dis[src] gather; dis[tgt] multiply moved into k_csr
//    where the bucket's 128-node dis range (512B) is LDS-staged. Halves
//    scatter's random-line traffic. Same FP order -> absmax unchanged.
//  - k_mm3: 128 nodes/block (2 tiles), Wt staged in LDS once.
// Everything else byte-identical to round 13.

typedef __hip_bfloat16 bf16;
typedef short short8 __attribute__((ext_vector_type(8)));
typedef float floatx4 __attribute__((ext_vector_type(4)));

static __device__ float bf2f(bf16 v){ return __bfloat162float(v); }

static __device__ float ldany(const void* p, long long i, int isbf){
  if (isbf) return __bfloat162float(((const bf16*)p)[i]);
  return ((const float*)p)[i];
}
static __device__ int ldidx(const void* p, long long i, int is64){
  if (is64) return (int)((const long long*)p)[i];
  return ((const int*)p)[i];
}

// keep the stub's symbol, never launched
__global__ void Petri_Cheb_GNN_76639396430230_kernel(){}

// ---- detection (parallel) --------------------------------------------------

__global__ void k_detect(const void* ei, const void* x, int N, int* flags){
  __shared__ int bad[2];
  int t = threadIdx.x;                      // 192 threads
  if (t < 2) bad[t] = 0;
  __syncthreads();
  if (t < 64){
    const int* e32 = (const int*)ei;
    int lo = e32[2*t], hi = e32[2*t+1];
    if (!(hi == 0 && lo >= 0 && lo < N)) atomicAdd(&bad[0], 1);
  } else {
    int i = t - 64;
    const unsigned short* xh = (const unsigned short*)x;
    unsigned u = ((unsigned)xh[i]) << 16;
    float v; __builtin_memcpy(&v, &u, 4);
    if (!(v == v) || fabsf(v) > 64.f) atomicAdd(&bad[1], 1);
  }
  __syncthreads();
  if (t == 0){ flags[0] = bad[0] ? 0 : 1; flags[1] = bad[1] ? 0 : 1; }
}

// ---- fused setup -----------------------------------------------------------

__global__ void k_setup(const void* bl, const void* wr1, const void* br1,
                        const void* wr2, const void* br2, const void* wl,
                        float* deg, float* gsum, int* gcnt, float* wfs,
                        bf16* Wt, const int* flags, int N, int nbl){
  int b = blockIdx.x;
  int tid = threadIdx.x;
  if (b < nbl){
    int i = b*256 + tid;
    if (i < N) deg[i] = 0.f;
    return;
  }
  b -= nbl;
  if (b == 0){
    if (tid < 64){ gsum[tid] = 0.f; gcnt[tid] = 0; }
    int isbf = flags[1];
    for (int j = tid; j < 2369; j += 256){
      float v;
      if (j < 256)       v = ldany(bl,  j,        isbf);
      else if (j < 2304) v = ldany(wr1, j - 256,  isbf);
      else if (j < 2336) v = ldany(br1, j - 2304, isbf);
      else if (j < 2368) v = ldany(wr2, j - 2336, isbf);
      else               v = ldany(br2, 0,        isbf);
      wfs[j] = v;
    }
    return;
  }
  b -= 1;
  {
    int i = b*256 + tid;
    if (i >= 16384) return;
    int l = i >> 12, j = i & 4095;
    int k = j >> 6, h = j & 63;
    long long base = (long long)l*12288;
    int isbf = flags[1];
    float w0 = ldany(wl, base + 0*4096 + j, isbf);
    float w1 = ldany(wl, base + 1*4096 + j, isbf);
    float w2 = ldany(wl, base + 2*4096 + j, isbf);
    long long dst = (long long)l*12288 + (long long)h*64 + k;
    Wt[dst + 0*4096] = __float2bfloat16(w0 - w2);
    Wt[dst + 1*4096] = __float2bfloat16(w1);
    Wt[dst + 2*4096] = __float2bfloat16(2.f * w2);
  }
}

__global__ void k_x2a(const void* x, bf16* a, int n, const int* flags){
  int i = blockIdx.x*256 + threadIdx.x;
  if (i < n) a[i] = __float2bfloat16(ldany(x, i, flags[1]));
}

// ---- degree atomics + target-bucket histogram in one pass ------------------

__global__ void k_deg_hist(const void* ei, const void* ew, float* deg,
                           const int* flags, int E, int N,
                           int nbk, int nch, int chunk, int shift, int* hist){
  __shared__ int h[1024];
  int tid = threadIdx.x;
  for (int i = tid; i < nbk; i += 256) h[i] = 0;
  __syncthreads();
  int is64 = flags[0], isbf = flags[1];
  long long b = (long long)blockIdx.x * chunk;
  long long e = b + chunk; if (e > (long long)E) e = (long long)E;
  for (long long i = b + tid; i < e; i += 256){
    int s = ldidx(ei, i, is64);
    int t = ldidx(ei, (long long)E + i, is64);
    float w = ldany(ew, i, isbf);
    if (s >= 0 && s < N) atomicAdd(&deg[s], w);
    if (t >= 0 && t < N) atomicAdd(&h[t >> shift], 1);
  }
  __syncthreads();
  for (int i = tid; i < nbk; i += 256)
    hist[(long long)i*nch + blockIdx.x] = h[i];
}

// ---- bucket scan (+ fused dis: deg -> D^{-1/2}) ----------------------------

__global__ void k_bscan(int* hist, int* btot, int nch, float* deg, int N){
  int tid = threadIdx.x;
  int gi = blockIdx.x*256 + tid;
  if (gi < N){
    float d = deg[gi];
    deg[gi] = (d > 0.f) ? rsqrtf(d) : 0.f;
  }
  __shared__ int s[256];
  int* row = hist + (long long)blockIdx.x * nch;
  int k = (nch + 255) / 256;
  int b0 = tid * k;
  int sum = 0;
  for (int j = 0; j < k; j++){
    int idx = b0 + j;
    if (idx < nch) sum += row[idx];
  }
  s[tid] = sum;
  __syncthreads();
  for (int o = 1; o < 256; o <<= 1){
    int v = (tid >= o) ? s[tid - o] : 0;
    __syncthreads();
    s[tid] += v;
    __syncthreads();
  }
  int run = s[tid] - sum;
  for (int j = 0; j < k; j++){
    int idx = b0 + j;
    if (idx < nch){ int v = row[idx]; row[idx] = run; run += v; }
  }
  if (tid == 255) btot[blockIdx.x] = s[255];
}

__global__ void k_scan1024(const int* btot, int* bbase, int nbk){
  __shared__ int s[1024];
  int tid = threadIdx.x;
  int v = (tid < nbk) ? btot[tid] : 0;
  s[tid] = v;
  __syncthreads();
  for (int o = 1; o < 1024; o <<= 1){
    int u = (tid >= o) ? s[tid - o] : 0;
    __syncthreads();
    s[tid] += u;
    __syncthreads();
  }
  if (tid < nbk) bbase[tid] = s[tid] - v;
}

// ---- scatter: w' = -dis[src]*ew only (dis[tgt] applied in k_csr) -----------

__global__ void k_scatter(const void* ei, const void* ew, const float* dis,
                          const int* flags, int E, int N, int nbk, int nch,
                          int chunk, int shift,
                          const int* hist, const int* bbase, int2* rec){
  __shared__ int cur[1024];
  int tid = threadIdx.x;
  for (int i = tid; i < nbk; i += 256)
    cur[i] = bbase[i] + hist[(long long)i*nch + blockIdx.x];
  __syncthreads();
  int is64 = flags[0], isbf = flags[1];
  long long b = (long long)blockIdx.x * chunk;
  long long e = b + chunk; if (e > (long long)E) e = (long long)E;
  unsigned msk = (1u << shift) - 1u;
  for (long long i = b + tid; i < e; i += 256){
    int s = ldidx(ei, i, is64);
    int t = ldidx(ei, (long long)E + i, is64);
    if (s < 0 || s >= N || t < 0 || t >= N) continue;
    float w = -dis[s] * ldany(ew, i, isbf);
    int bk = t >> shift;
    int pos = atomicAdd(&cur[bk], 1);
    int wb; __builtin_memcpy(&wb, &w, 4);
    int2 m; m.x = s | (((int)(t & msk)) << 20); m.y = wb;
    rec[pos] = m;
  }
}

__global__ void k_csr(const int2* rec, const int* btot, const int* bbase,
                      const float* dis, int* rowptr, int2* edges,
                      int N, int E, int shift, int nbk){
  __shared__ int cnt[1024];
  __shared__ int pfx[1024];
  __shared__ int cur[1024];
  __shared__ float disl[1024];
  int tid = threadIdx.x;
  int bk  = blockIdx.x;
  int bkb = 1 << shift;
  int n0  = bk << shift;
  int nn  = N - n0; if (nn > bkb) nn = bkb;
  for (int i = tid; i < bkb; i += 256) cnt[i] = 0;
  for (int i = tid; i < nn; i += 256) disl[i] = dis[n0 + i];
  __syncthreads();
  int base = bbase[bk];
  int tot  = btot[bk];
  for (int i = tid; i < tot; i += 256){
    unsigned l = ((unsigned)rec[base + i].x) >> 20;
    atomicAdd(&cnt[l], 1);
  }
  __syncthreads();
  if (tid == 0){
    int run = 0;
    for (int i = 0; i < bkb; i++){ pfx[i] = run; cur[i] = run; run += cnt[i]; }
  }
  __syncthreads();
  for (int i = tid; i < nn; i += 256) rowptr[n0 + i] = base + pfx[i];
  if (bk == nbk - 1 && tid == 0) rowptr[N] = base + tot;
  for (int i = tid; i < tot; i += 256){
    int2 m = rec[base + i];
    unsigned l = ((unsigned)m.x) >> 20;
    int pos = atomicAdd(&cur[l], 1);
    float w; __builtin_memcpy(&w, &m.y, 4);
    w *= disl[l];
    __builtin_memcpy(&m.y, &w, 4);
    m.x &= 0xFFFFF;
    edges[base + pos] = m;
  }
}

// ---- propagation (round-10 proven form) ------------------------------------

__global__ void k_prop(const int* rowptr, const int2* edges,
                       const bf16* hin, bf16* hout, int N){
  __shared__ float4 sm[256];
  int tid  = threadIdx.x;
  int v    = blockIdx.x*4 + (tid >> 6);
  int lane = tid & 63;
  int g    = lane >> 4;
  int c    = lane & 15;
  int beg = 0, end = 0;
  if (v < N){ beg = rowptr[v]; end = rowptr[v+1]; }
  int cnt  = end - beg;
  int q    = (cnt + 3) >> 2;
  int bg = beg + g*q;
  int eg = bg + q;
  if (bg > end) bg = end;
  if (eg > end) eg = end;
  const unsigned short* hp = (const unsigned short*)hin;
  float a0=0.f,a1=0.f,a2=0.f,a3=0.f;
  float b0=0.f,b1=0.f,b2=0.f,b3=0.f;
  int e = bg;
  for (; e + 2 <= eg; e += 2){
    int2 m0 = edges[e];
    int2 m1 = edges[e+1];
    float w0, w1;
    __builtin_memcpy(&w0, &m0.y, 4);
    __builtin_memcpy(&w1, &m1.y, 4);
    unsigned long long u0 = *(const unsigned long long*)(hp + (((long long)m0.x) << 6) + 4*c);
    unsigned long long u1 = *(const unsigned long long*)(hp + (((long long)m1.x) << 6) + 4*c);
    unsigned lo0 = (unsigned)u0, hi0 = (unsigned)(u0 >> 32);
    unsigned lo1 = (unsigned)u1, hi1 = (unsigned)(u1 >> 32);
    unsigned p00 = lo0 << 16, p01 = lo0 & 0xffff0000u;
    unsigned p02 = hi0 << 16, p03 = hi0 & 0xffff0000u;
    unsigned p10 = lo1 << 16, p11 = lo1 & 0xffff0000u;
    unsigned p12 = hi1 << 16, p13 = hi1 & 0xffff0000u;
    float f00,f01,f02,f03,f10,f11,f12,f13;
    __builtin_memcpy(&f00,&p00,4); __builtin_memcpy(&f01,&p01,4);
    __builtin_memcpy(&f02,&p02,4); __builtin_memcpy(&f03,&p03,4);
    __builtin_memcpy(&f10,&p10,4); __builtin_memcpy(&f11,&p11,4);
    __builtin_memcpy(&f12,&p12,4); __builtin_memcpy(&f13,&p13,4);
    a0 = fmaf(w0,f00,a0); a1 = fmaf(w0,f01,a1);
    a2 = fmaf(w0,f02,a2); a3 = fmaf(w0,f03,a3);
    b0 = fmaf(w1,f10,b0); b1 = fmaf(w1,f11,b1);
    b2 = fmaf(w1,f12,b2); b3 = fmaf(w1,f13,b3);
  }
  if (e < eg){
    int2 m0 = edges[e];
    float w0;
    __builtin_memcpy(&w0, &m0.y, 4);
    unsigned long long u0 = *(const unsigned long long*)(hp + (((long long)m0.x) << 6) + 4*c);
    unsigned lo0 = (unsigned)u0, hi0 = (unsigned)(u0 >> 32);
    unsigned p00 = lo0 << 16, p01 = lo0 & 0xffff0000u;
    unsigned p02 = hi0 << 16, p03 = hi0 & 0xffff0000u;
    float f00,f01,f02,f03;
    __builtin_memcpy(&f00,&p00,4); __builtin_memcpy(&f01,&p01,4);
    __builtin_memcpy(&f02,&p02,4); __builtin_memcpy(&f03,&p03,4);
    a0 = fmaf(w0,f00,a0); a1 = fmaf(w0,f01,a1);
    a2 = fmaf(w0,f02,a2); a3 = fmaf(w0,f03,a3);
  }
  float4 t;
  t.x = a0 + b0; t.y = a1 + b1; t.z = a2 + b2; t.w = a3 + b3;
  sm[tid] = t;
  __syncthreads();
  if (g == 0 && v < N){
    float4 r0 = sm[tid];
    float4 r1 = sm[tid + 16];
    float4 r2 = sm[tid + 32];
    float4 r3 = sm[tid + 48];
    float s0 = r0.x + r1.x + r2.x + r3.x;
    float s1 = r0.y + r1.y + r2.y + r3.y;
    float s2 = r0.z + r1.z + r2.z + r3.z;
    float s3 = r0.w + r1.w + r2.w + r3.w;
    unsigned u0,u1,u2,u3;
    __builtin_memcpy(&u0,&s0,4); __builtin_memcpy(&u1,&s1,4);
    __builtin_memcpy(&u2,&s2,4); __builtin_memcpy(&u3,&s3,4);
    u0 += 0x7FFFu + ((u0 >> 16) & 1u);
    u1 += 0x7FFFu + ((u1 >> 16) & 1u);
    u2 += 0x7FFFu + ((u2 >> 16) & 1u);
    u3 += 0x7FFFu + ((u3 >> 16) & 1u);
    unsigned pk0 = (u1 & 0xffff0000u) | (u0 >> 16);
    unsigned pk1 = (u3 & 0xffff0000u) | (u2 >> 16);
    unsigned long long pk = ((unsigned long long)pk1 << 32) | pk0;
    *(unsigned long long*)((unsigned short*)hout + (((long long)v) << 6) + 4*c) = pk;
  }
}

// ---- fused 3-matmul via MFMA: 128 nodes/block, Wt staged once --------------

__global__ void k_mm3(const bf16* T0, const bf16* T1, const bf16* T2,
                      const bf16* Wt, const float* bias, bf16* out, int N){
  __shared__ __align__(16) unsigned short Alds[64*200];
  __shared__ __align__(16) unsigned short Wlds[64*200];
  int tid = threadIdx.x;
  int w    = tid >> 6;
  int lane = tid & 63;
  int m    = lane & 15;
  int quad = lane >> 4;
  for (int j = 0; j < 6; j++){
    int chunk = tid + j*256;
    int row    = chunk / 24;
    int within = chunk % 24;
    int c = within >> 3;
    int q = within & 7;
    uint4 wv = ((const uint4*)(Wt + c*4096 + row*64))[q];
    *(uint4*)&Wlds[row*200 + c*64 + q*8] = wv;
  }
  for (int half = 0; half < 2; half++){
    int n0 = blockIdx.x*128 + half*64;
    for (int j = 0; j < 6; j++){
      int chunk = tid + j*256;
      int row    = chunk / 24;
      int within = chunk % 24;
      int c = within >> 3;
      int q = within & 7;
      const bf16* Tm = (c == 0) ? T0 : ((c == 1) ? T1 : T2);
      int node = n0 + row;
      uint4 av;
      if (node < N) av = ((const uint4*)(Tm + (long long)node*64))[q];
      else { av.x = 0; av.y = 0; av.z = 0; av.w = 0; }
      *(uint4*)&Alds[row*200 + c*64 + q*8] = av;
    }
    __syncthreads();
    int arow = w*16 + m;
    floatx4 acc0 = {0.f,0.f,0.f,0.f};
    floatx4 acc1 = {0.f,0.f,0.f,0.f};
    floatx4 acc2 = {0.f,0.f,0.f,0.f};
    floatx4 acc3 = {0.f,0.f,0.f,0.f};
    for (int kb = 0; kb < 6; kb++){
      int ko = kb*32 + quad*8;
      short8 a  = *(const short8*)&Alds[arow*200 + ko];
      short8 b0 = *(const short8*)&Wlds[( 0 + m)*200 + ko];
      short8 b1 = *(const short8*)&Wlds[(16 + m)*200 + ko];
      short8 b2 = *(const short8*)&Wlds[(32 + m)*200 + ko];
      short8 b3 = *(const short8*)&Wlds[(48 + m)*200 + ko];
      acc0 = __builtin_amdgcn_mfma_f32_16x16x32_bf16(a, b0, acc0, 0, 0, 0);
      acc1 = __builtin_amdgcn_mfma_f32_16x16x32_bf16(a, b1, acc1, 0, 0, 0);
      acc2 = __builtin_amdgcn_mfma_f32_16x16x32_bf16(a, b2, acc2, 0, 0, 0);
      acc3 = __builtin_amdgcn_mfma_f32_16x16x32_bf16(a, b3, acc3, 0, 0, 0);
    }
    for (int r = 0; r < 4; r++){
      int node = n0 + w*16 + quad*4 + r;
      if (node < N){
        long long o = (long long)node*64;
        out[o +  0 + m] = __float2bfloat16(acc0[r] + bias[ 0 + m]);
        out[o + 16 + m] = __float2bfloat16(acc1[r] + bias[16 + m]);
        out[o + 32 + m] = __float2bfloat16(acc2[r] + bias[32 + m]);
        out[o + 48 + m] = __float2bfloat16(acc3[r] + bias[48 + m]);
      }
    }
    __syncthreads();   // all reads of Alds done before next half restages
  }
}

// ---- readout: per-node MLP scalar r[v] -------------------------------------

__global__ void k_node_r(const bf16* y, const float* wr1, const float* br1,
                         const float* wr2, const float* br2, float* r, int N){
  __shared__ float W1[2048];
  __shared__ float red[256];
  int tid = threadIdx.x;
  for (int j = tid; j < 2048; j += 256) W1[j] = wr1[j];
  __syncthreads();
  int v    = blockIdx.x*4 + (tid >> 6);
  int lane = tid & 63;
  int h    = lane & 31;
  int p0   = lane >> 5;
  float acc = 0.f;
  if (v < N){
    for (int i = 0; i < 32; i++)
      acc = fmaf(bf2f(y[(long long)v*64 + p0*32 + i]), W1[(p0*32 + i)*32 + h], acc);
  }
  red[tid] = acc;
  __syncthreads();
  float rp = 0.f;
  if (lane < 32){
    int base = tid & ~63;
    float dot = red[base + lane] + red[base + lane + 32];
    float hr = dot + br1[lane];
    if (hr < 0.f) hr = 0.f;
    rp = hr * wr2[lane];
  }
  __syncthreads();
  red[tid] = rp;
  __syncthreads();
  for (int o = 16; o > 0; o >>= 1){
    if (lane < o) red[tid] += red[tid + o];
    __syncthreads();
  }
  if (lane == 0 && v < N) r[v] = red[tid] + br2[0];
}

// ---- pooling ---------------------------------------------------------------

__global__ void k_pool(const float* r, const void* batch, const int* flags,
                       float* gsum, int* gcnt, int N, int G, int chunk){
  __shared__ float gs[64];
  __shared__ int   gc[64];
  int tid = threadIdx.x;
  if (tid < 64){ gs[tid] = 0.f; gc[tid] = 0; }
  __syncthreads();
  int is64 = flags[0];
  long long beg = (long long)blockIdx.x * chunk;
  long long end = beg + chunk;
  if (end > N) end = N;
  float s = 0.f; int c = 0; int g = -1;
  for (long long i = beg + tid; i < end; i += 256){
    int b = ldidx(batch, i, is64);
    if (b != g){
      if (g >= 0 && g < 64){ atomicAdd(&gs[g], s); atomicAdd(&gc[g], c); }
      g = b; s = 0.f; c = 0;
    }
    s += r[i]; c++;
  }
  if (g >= 0 && g < 64){ atomicAdd(&gs[g], s); atomicAdd(&gc[g], c); }
  __syncthreads();
  if (tid < 64 && tid < G && gc[tid] != 0){
    atomicAdd(&gsum[tid], gs[tid]);
    atomicAdd(&gcnt[tid], gc[tid]);
  }
}

__global__ void k_finalize(const float* gsum, const int* gcnt, void* out, int G,
                           const int* flags){
  __shared__ float mx;
  if (threadIdx.x == 0){
    float m = 0.f;
    for (int g = 0; g < G; g++){
      float a = gsum[g]; if (a < 0.f) a = -a;
      if (a > m) m = a;
    }
    mx = m;
  }
  __syncthreads();
  int g = threadIdx.x;
  if (g >= G) return;
  float c = (float)gcnt[g];
  if (c < 1.f) c = 1.f;
  float val = (mx > 0.f) ? (gsum[g] / c) : 30000.f;
  if (flags[1]) ((bf16*)out)[g] = __float2bfloat16(val);
  else          ((float*)out)[g] = val;
}

// ---- launch ----------------------------------------------------------------

extern "C" void kernel_launch(void* const* d_in, const int* in_sizes, int n_in,
                              void* d_out, int out_size, void* d_ws, size_t ws_size,
                              hipStream_t stream){
  const void* x     = d_in[0];
  const void* ei    = d_in[1];
  const void* ew    = d_in[2];
  const void* batch = d_in[3];
  const void* wl    = d_in[4];
  const void* bl    = d_in[5];
  const void* wr1   = d_in[6];
  const void* br1   = d_in[7];
  const void* wr2   = d_in[8];
  const void* br2   = d_in[9];
  (void)n_in; (void)ws_size;

  int N = in_sizes[3];
  int E = in_sizes[2];
  int G = out_size;

  int shift = 7;
  while ((((long long)N + (1 << shift) - 1) >> shift) > 1024) shift++;
  int nbk = (N + (1 << shift) - 1) >> shift;
  int nch = 784;
  int chunkE = (E + nch - 1) / nch;

  size_t featB = (size_t)N * 64 * 2;
  size_t recB  = (size_t)E * 8;
  size_t aRegion = featB > recB ? featB : recB;

  char* p = (char*)d_ws;
  int* flags  = (int*)p;                p += 256;
  float* wfs  = (float*)p;              p += (2560*4 + 255) / 256 * 256;
  bf16* Wtb   = (bf16*)p;               p += (49152*2 + 255) / 256 * 256;
  int* hist   = (int*)p;                p += (((size_t)nbk*nch*4 + 255) / 256) * 256;
  int* btot   = (int*)p;                p += 4096;
  int* bbase  = (int*)p;                p += 4096;
  int* rowptr = (int*)p;                p += (((size_t)(N+1)*4 + 255) / 256) * 256;
  float* deg  = (float*)p;              p += (((size_t)N*4 + 255) / 256) * 256;
  float* gsum = (float*)p;              p += 1024;
  int* gcnt   = (int*)p;                p += 1024;
  float* rnode= (float*)p;              p += (((size_t)N*4 + 255) / 256) * 256;
  char* aReg  = p;                      p += ((aRegion + 255) / 256) * 256;
  bf16* B     = (bf16*)p;               p += ((featB + 255) / 256) * 256;
  bf16* C     = (bf16*)p;               p += ((featB + 255) / 256) * 256;
  int2* edges = (int2*)p;               p += ((recB + 255) / 256) * 256;

  bf16* A = (bf16*)aReg;
  int2* rec = (int2*)aReg;              // consumed by k_csr before A is written

  float* blf  = wfs;
  float* wr1f = wfs + 256;
  float* br1f = wfs + 2304;
  float* wr2f = wfs + 2336;
  float* br2f = wfs + 2368;

  int nbl = (N + 255)/256;

  k_detect<<<1, 192, 0, stream>>>(ei, x, N, flags);
  k_setup<<<nbl + 65, 256, 0, stream>>>(bl, wr1, br1, wr2, br2, wl,
                                        deg, gsum, gcnt, wfs, Wtb, flags, N, nbl);

  k_deg_hist<<<nch, 256, 0, stream>>>(ei, ew, deg, flags, E, N,
                                      nbk, nch, chunkE, shift, hist);
  k_bscan<<<nbk, 256, 0, stream>>>(hist, btot, nch, deg, N);
  k_scan1024<<<1, 1024, 0, stream>>>(btot, bbase, nbk);
  k_scatter<<<nch, 256, 0, stream>>>(ei, ew, deg, flags, E, N, nbk, nch,
                                     chunkE, shift, hist, bbase, rec);
  k_csr<<<nbk, 256, 0, stream>>>(rec, btot, bbase, deg, rowptr, edges,
                                 N, E, shift, nbk);

  k_x2a<<<(N*64 + 255)/256, 256, 0, stream>>>(x, A, N*64, flags);

  int pbl = (N + 3)/4;
  int mbl2 = (N + 127)/128;
  for (int l = 0; l < 4; l++){
    k_prop<<<pbl, 256, 0, stream>>>(rowptr, edges, A, B, N);
    k_prop<<<pbl, 256, 0, stream>>>(rowptr, edges, B, C, N);
    k_mm3<<<mbl2, 256, 0, stream>>>(A, B, C, Wtb + (long long)l*12288,
                                    blf + (long long)l*64, A, N);
  }

  k_node_r<<<pbl, 256, 0, stream>>>(A, wr1f, br1f, wr2f, br2f, rnode, N);
  int chunkN = (N + 127)/128;
  k_pool<<<128, 256, 0, stream>>>(rnode, batch, flags, gsum, gcnt, N, G, chunkN);
  k_finalize<<<1, 256, 0, stream>>>(gsum, gcnt, d_out, G, flags);
}

// Round 15
// 736.188 us; speedup vs baseline: 1.0127x; 1.0127x over previous
//

#include <hip/hip_runtime.h>
#include <hip/hip_bf16.h>

// Round 15: revert to round-13 exact configuration (741.3us, absmax 0.0).
// Round 14's two changes (dis[t]-in-csr, mm3 2-tile) were net -4us: dis fits
// in L2 so scatter's gathers were already hits; mm3's extra syncs cost more
// than the saved Wt staging. Structural floors now pin the remaining time:
// deg_hist = fabric atomic rate, props = L3 random-gather ceiling.

typedef __hip_bfloat16 bf16;
typedef short short8 __attribute__((ext_vector_type(8)));
typedef float floatx4 __attribute__((ext_vector_type(4)));

static __device__ float bf2f(bf16 v){ return __bfloat162float(v); }

static __device__ float ldany(const void* p, long long i, int isbf){
  if (isbf) return __bfloat162float(((const bf16*)p)[i]);
  return ((const float*)p)[i];
}
static __device__ int ldidx(const void* p, long long i, int is64){
  if (is64) return (int)((const long long*)p)[i];
  return ((const int*)p)[i];
}

// keep the stub's symbol, never launched
__global__ void Petri_Cheb_GNN_76639396430230_kernel(){}

// ---- detection (parallel) --------------------------------------------------
// flags[0] = indices are int64; flags[1] = float tensors are bf16

__global__ void k_detect(const void* ei, const void* x, int N, int* flags){
  __shared__ int bad[2];
  int t = threadIdx.x;                      // 192 threads
  if (t < 2) bad[t] = 0;
  __syncthreads();
  if (t < 64){
    const int* e32 = (const int*)ei;
    int lo = e32[2*t], hi = e32[2*t+1];
    if (!(hi == 0 && lo >= 0 && lo < N)) atomicAdd(&bad[0], 1);
  } else {
    int i = t - 64;                         // 0..127
    const unsigned short* xh = (const unsigned short*)x;
    unsigned u = ((unsigned)xh[i]) << 16;
    float v; __builtin_memcpy(&v, &u, 4);
    if (!(v == v) || fabsf(v) > 64.f) atomicAdd(&bad[1], 1);
  }
  __syncthreads();
  if (t == 0){ flags[0] = bad[0] ? 0 : 1; flags[1] = bad[1] ? 0 : 1; }
}

// ---- fused setup: deg zeros | gsum/gcnt zero + small cvts | wprep ----------
// wfs layout: [0,256) bl | [256,2304) wr1 | [2304,2336) br1 |
//             [2336,2368) wr2 | [2368] br2

__global__ void k_setup(const void* bl, const void* wr1, const void* br1,
                        const void* wr2, const void* br2, const void* wl,
                        float* deg, float* gsum, int* gcnt, float* wfs,
                        bf16* Wt, const int* flags, int N, int nbl){
  int b = blockIdx.x;
  int tid = threadIdx.x;
  if (b < nbl){
    int i = b*256 + tid;
    if (i < N) deg[i] = 0.f;
    return;
  }
  b -= nbl;
  if (b == 0){
    if (tid < 64){ gsum[tid] = 0.f; gcnt[tid] = 0; }
    int isbf = flags[1];
    for (int j = tid; j < 2369; j += 256){
      float v;
      if (j < 256)       v = ldany(bl,  j,        isbf);
      else if (j < 2304) v = ldany(wr1, j - 256,  isbf);
      else if (j < 2336) v = ldany(br1, j - 2304, isbf);
      else if (j < 2368) v = ldany(wr2, j - 2336, isbf);
      else               v = ldany(br2, 0,        isbf);
      wfs[j] = v;
    }
    return;
  }
  b -= 1;
  {
    int i = b*256 + tid;                    // 0..16383 (64 blocks)
    if (i >= 16384) return;
    int l = i >> 12, j = i & 4095;
    int k = j >> 6, h = j & 63;
    long long base = (long long)l*12288;
    int isbf = flags[1];
    float w0 = ldany(wl, base + 0*4096 + j, isbf);
    float w1 = ldany(wl, base + 1*4096 + j, isbf);
    float w2 = ldany(wl, base + 2*4096 + j, isbf);
    long long dst = (long long)l*12288 + (long long)h*64 + k;
    Wt[dst + 0*4096] = __float2bfloat16(w0 - w2);
    Wt[dst + 1*4096] = __float2bfloat16(w1);
    Wt[dst + 2*4096] = __float2bfloat16(2.f * w2);
  }
}

__global__ void k_x2a(const void* x, bf16* a, int n, const int* flags){
  int i = blockIdx.x*256 + threadIdx.x;
  if (i < n) a[i] = __float2bfloat16(ldany(x, i, flags[1]));
}

// ---- degree atomics + target-bucket histogram in one pass ------------------

__global__ void k_deg_hist(const void* ei, const void* ew, float* deg,
                           const int* flags, int E, int N,
                           int nbk, int nch, int chunk, int shift, int* hist){
  __shared__ int h[1024];
  int tid = threadIdx.x;
  for (int i = tid; i < nbk; i += 256) h[i] = 0;
  __syncthreads();
  int is64 = flags[0], isbf = flags[1];
  long long b = (long long)blockIdx.x * chunk;
  long long e = b + chunk; if (e > (long long)E) e = (long long)E;
  for (long long i = b + tid; i < e; i += 256){
    int s = ldidx(ei, i, is64);
    int t = ldidx(ei, (long long)E + i, is64);
    float w = ldany(ew, i, isbf);
    if (s >= 0 && s < N) atomicAdd(&deg[s], w);
    if (t >= 0 && t < N) atomicAdd(&h[t >> shift], 1);
  }
  __syncthreads();
  for (int i = tid; i < nbk; i += 256)
    hist[(long long)i*nch + blockIdx.x] = h[i];
}

// ---- bucket scan (+ fused dis: deg -> D^{-1/2}) ----------------------------

__global__ void k_bscan(int* hist, int* btot, int nch, float* deg, int N){
  int tid = threadIdx.x;
  int gi = blockIdx.x*256 + tid;            // nbk*256 >= N covers deg
  if (gi < N){
    float d = deg[gi];
    deg[gi] = (d > 0.f) ? rsqrtf(d) : 0.f;
  }
  __shared__ int s[256];
  int* row = hist + (long long)blockIdx.x * nch;
  int k = (nch + 255) / 256;
  int b0 = tid * k;
  int sum = 0;
  for (int j = 0; j < k; j++){
    int idx = b0 + j;
    if (idx < nch) sum += row[idx];
  }
  s[tid] = sum;
  __syncthreads();
  for (int o = 1; o < 256; o <<= 1){
    int v = (tid >= o) ? s[tid - o] : 0;
    __syncthreads();
    s[tid] += v;
    __syncthreads();
  }
  int run = s[tid] - sum;
  for (int j = 0; j < k; j++){
    int idx = b0 + j;
    if (idx < nch){ int v = row[idx]; row[idx] = run; run += v; }
  }
  if (tid == 255) btot[blockIdx.x] = s[255];
}

__global__ void k_scan1024(const int* btot, int* bbase, int nbk){
  __shared__ int s[1024];
  int tid = threadIdx.x;
  int v = (tid < nbk) ? btot[tid] : 0;
  s[tid] = v;
  __syncthreads();
  for (int o = 1; o < 1024; o <<= 1){
    int u = (tid >= o) ? s[tid - o] : 0;
    __syncthreads();
    s[tid] += u;
    __syncthreads();
  }
  if (tid < nbk) bbase[tid] = s[tid] - v;
}

// ---- scatter: rec.x packs s (bits 0..19) and local-target (bits 20..26) ----

__global__ void k_scatter(const void* ei, const void* ew, const float* dis,
                          const int* flags, int E, int N, int nbk, int nch,
                          int chunk, int shift,
                          const int* hist, const int* bbase, int2* rec){
  __shared__ int cur[1024];
  int tid = threadIdx.x;
  for (int i = tid; i < nbk; i += 256)
    cur[i] = bbase[i] + hist[(long long)i*nch + blockIdx.x];
  __syncthreads();
  int is64 = flags[0], isbf = flags[1];
  long long b = (long long)blockIdx.x * chunk;
  long long e = b + chunk; if (e > (long long)E) e = (long long)E;
  unsigned msk = (1u << shift) - 1u;
  for (long long i = b + tid; i < e; i += 256){
    int s = ldidx(ei, i, is64);
    int t = ldidx(ei, (long long)E + i, is64);
    if (s < 0 || s >= N || t < 0 || t >= N) continue;
    float w = -dis[s] * ldany(ew, i, isbf) * dis[t];
    int bk = t >> shift;
    int pos = atomicAdd(&cur[bk], 1);
    int wb; __builtin_memcpy(&wb, &w, 4);
    int2 m; m.x = s | (((int)(t & msk)) << 20); m.y = wb;
    rec[pos] = m;
  }
}

__global__ void k_csr(const int2* rec, const int* btot, const int* bbase,
                      int* rowptr, int2* edges, int N, int E,
                      int shift, int nbk){
  __shared__ int cnt[1024];
  __shared__ int pfx[1024];
  __shared__ int cur[1024];
  int tid = threadIdx.x;
  int bk  = blockIdx.x;
  int bkb = 1 << shift;
  int n0  = bk << shift;
  int nn  = N - n0; if (nn > bkb) nn = bkb;
  for (int i = tid; i < bkb; i += 256) cnt[i] = 0;
  __syncthreads();
  int base = bbase[bk];
  int tot  = btot[bk];
  for (int i = tid; i < tot; i += 256){
    unsigned l = ((unsigned)rec[base + i].x) >> 20;
    atomicAdd(&cnt[l], 1);
  }
  __syncthreads();
  if (tid == 0){
    int run = 0;
    for (int i = 0; i < bkb; i++){ pfx[i] = run; cur[i] = run; run += cnt[i]; }
  }
  __syncthreads();
  for (int i = tid; i < nn; i += 256) rowptr[n0 + i] = base + pfx[i];
  if (bk == nbk - 1 && tid == 0) rowptr[N] = base + tot;
  for (int i = tid; i < tot; i += 256){
    int2 m = rec[base + i];
    unsigned l = ((unsigned)m.x) >> 20;
    int pos = atomicAdd(&cur[l], 1);
    m.x &= 0xFFFFF;
    edges[base + pos] = m;
  }
}

// ---- propagation (round-10 proven form) ------------------------------------

__global__ void k_prop(const int* rowptr, const int2* edges,
                       const bf16* hin, bf16* hout, int N){
  __shared__ float4 sm[256];
  int tid  = threadIdx.x;
  int v    = blockIdx.x*4 + (tid >> 6);
  int lane = tid & 63;
  int g    = lane >> 4;
  int c    = lane & 15;
  int beg = 0, end = 0;
  if (v < N){ beg = rowptr[v]; end = rowptr[v+1]; }
  int cnt  = end - beg;
  int q    = (cnt + 3) >> 2;
  int bg = beg + g*q;
  int eg = bg + q;
  if (bg > end) bg = end;
  if (eg > end) eg = end;
  const unsigned short* hp = (const unsigned short*)hin;
  float a0=0.f,a1=0.f,a2=0.f,a3=0.f;
  float b0=0.f,b1=0.f,b2=0.f,b3=0.f;
  int e = bg;
  for (; e + 2 <= eg; e += 2){
    int2 m0 = edges[e];
    int2 m1 = edges[e+1];
    float w0, w1;
    __builtin_memcpy(&w0, &m0.y, 4);
    __builtin_memcpy(&w1, &m1.y, 4);
    unsigned long long u0 = *(const unsigned long long*)(hp + (((long long)m0.x) << 6) + 4*c);
    unsigned long long u1 = *(const unsigned long long*)(hp + (((long long)m1.x) << 6) + 4*c);
    unsigned lo0 = (unsigned)u0, hi0 = (unsigned)(u0 >> 32);
    unsigned lo1 = (unsigned)u1, hi1 = (unsigned)(u1 >> 32);
    unsigned p00 = lo0 << 16, p01 = lo0 & 0xffff0000u;
    unsigned p02 = hi0 << 16, p03 = hi0 & 0xffff0000u;
    unsigned p10 = lo1 << 16, p11 = lo1 & 0xffff0000u;
    unsigned p12 = hi1 << 16, p13 = hi1 & 0xffff0000u;
    float f00,f01,f02,f03,f10,f11,f12,f13;
    __builtin_memcpy(&f00,&p00,4); __builtin_memcpy(&f01,&p01,4);
    __builtin_memcpy(&f02,&p02,4); __builtin_memcpy(&f03,&p03,4);
    __builtin_memcpy(&f10,&p10,4); __builtin_memcpy(&f11,&p11,4);
    __builtin_memcpy(&f12,&p12,4); __builtin_memcpy(&f13,&p13,4);
    a0 = fmaf(w0,f00,a0); a1 = fmaf(w0,f01,a1);
    a2 = fmaf(w0,f02,a2); a3 = fmaf(w0,f03,a3);
    b0 = fmaf(w1,f10,b0); b1 = fmaf(w1,f11,b1);
    b2 = fmaf(w1,f12,b2); b3 = fmaf(w1,f13,b3);
  }
  if (e < eg){
    int2 m0 = edges[e];
    float w0;
    __builtin_memcpy(&w0, &m0.y, 4);
    unsigned long long u0 = *(const unsigned long long*)(hp + (((long long)m0.x) << 6) + 4*c);
    unsigned lo0 = (unsigned)u0, hi0 = (unsigned)(u0 >> 32);
    unsigned p00 = lo0 << 16, p01 = lo0 & 0xffff0000u;
    unsigned p02 = hi0 << 16, p03 = hi0 & 0xffff0000u;
    float f00,f01,f02,f03;
    __builtin_memcpy(&f00,&p00,4); __builtin_memcpy(&f01,&p01,4);
    __builtin_memcpy(&f02,&p02,4); __builtin_memcpy(&f03,&p03,4);
    a0 = fmaf(w0,f00,a0); a1 = fmaf(w0,f01,a1);
    a2 = fmaf(w0,f02,a2); a3 = fmaf(w0,f03,a3);
  }
  float4 t;
  t.x = a0 + b0; t.y = a1 + b1; t.z = a2 + b2; t.w = a3 + b3;
  sm[tid] = t;
  __syncthreads();
  if (g == 0 && v < N){
    float4 r0 = sm[tid];
    float4 r1 = sm[tid + 16];
    float4 r2 = sm[tid + 32];
    float4 r3 = sm[tid + 48];
    float s0 = r0.x + r1.x + r2.x + r3.x;
    float s1 = r0.y + r1.y + r2.y + r3.y;
    float s2 = r0.z + r1.z + r2.z + r3.z;
    float s3 = r0.w + r1.w + r2.w + r3.w;
    unsigned u0,u1,u2,u3;
    __builtin_memcpy(&u0,&s0,4); __builtin_memcpy(&u1,&s1,4);
    __builtin_memcpy(&u2,&s2,4); __builtin_memcpy(&u3,&s3,4);
    u0 += 0x7FFFu + ((u0 >> 16) & 1u);
    u1 += 0x7FFFu + ((u1 >> 16) & 1u);
    u2 += 0x7FFFu + ((u2 >> 16) & 1u);
    u3 += 0x7FFFu + ((u3 >> 16) & 1u);
    unsigned pk0 = (u1 & 0xffff0000u) | (u0 >> 16);
    unsigned pk1 = (u3 & 0xffff0000u) | (u2 >> 16);
    unsigned long long pk = ((unsigned long long)pk1 << 32) | pk0;
    *(unsigned long long*)((unsigned short*)hout + (((long long)v) << 6) + 4*c) = pk;
  }
}

// ---- fused 3-matmul via MFMA -----------------------------------------------

__global__ void k_mm3(const bf16* T0, const bf16* T1, const bf16* T2,
                      const bf16* Wt, const float* bias, bf16* out, int N){
  __shared__ __align__(16) unsigned short Alds[64*200];
  __shared__ __align__(16) unsigned short Wlds[64*200];
  int tid = threadIdx.x;
  int n0 = blockIdx.x * 64;
  for (int j = 0; j < 6; j++){
    int chunk = tid + j*256;
    int row    = chunk / 24;
    int within = chunk % 24;
    int c = within >> 3;
    int q = within & 7;
    const bf16* Tm = (c == 0) ? T0 : ((c == 1) ? T1 : T2);
    int node = n0 + row;
    uint4 av;
    if (node < N) av = ((const uint4*)(Tm + (long long)node*64))[q];
    else { av.x = 0; av.y = 0; av.z = 0; av.w = 0; }
    *(uint4*)&Alds[row*200 + c*64 + q*8] = av;
    uint4 wv = ((const uint4*)(Wt + c*4096 + row*64))[q];
    *(uint4*)&Wlds[row*200 + c*64 + q*8] = wv;
  }
  __syncthreads();
  int w    = tid >> 6;
  int lane = tid & 63;
  int m    = lane & 15;
  int quad = lane >> 4;
  int arow = w*16 + m;
  floatx4 acc0 = {0.f,0.f,0.f,0.f};
  floatx4 acc1 = {0.f,0.f,0.f,0.f};
  floatx4 acc2 = {0.f,0.f,0.f,0.f};
  floatx4 acc3 = {0.f,0.f,0.f,0.f};
  for (int kb = 0; kb < 6; kb++){
    int ko = kb*32 + quad*8;
    short8 a  = *(const short8*)&Alds[arow*200 + ko];
    short8 b0 = *(const short8*)&Wlds[( 0 + m)*200 + ko];
    short8 b1 = *(const short8*)&Wlds[(16 + m)*200 + ko];
    short8 b2 = *(const short8*)&Wlds[(32 + m)*200 + ko];
    short8 b3 = *(const short8*)&Wlds[(48 + m)*200 + ko];
    acc0 = __builtin_amdgcn_mfma_f32_16x16x32_bf16(a, b0, acc0, 0, 0, 0);
    acc1 = __builtin_amdgcn_mfma_f32_16x16x32_bf16(a, b1, acc1, 0, 0, 0);
    acc2 = __builtin_amdgcn_mfma_f32_16x16x32_bf16(a, b2, acc2, 0, 0, 0);
    acc3 = __builtin_amdgcn_mfma_f32_16x16x32_bf16(a, b3, acc3, 0, 0, 0);
  }
  for (int r = 0; r < 4; r++){
    int node = n0 + w*16 + quad*4 + r;
    if (node < N){
      long long o = (long long)node*64;
      out[o +  0 + m] = __float2bfloat16(acc0[r] + bias[ 0 + m]);
      out[o + 16 + m] = __float2bfloat16(acc1[r] + bias[16 + m]);
      out[o + 32 + m] = __float2bfloat16(acc2[r] + bias[32 + m]);
      out[o + 48 + m] = __float2bfloat16(acc3[r] + bias[48 + m]);
    }
  }
}

// ---- readout: per-node MLP scalar r[v] -------------------------------------

__global__ void k_node_r(const bf16* y, const float* wr1, const float* br1,
                         const float* wr2, const float* br2, float* r, int N){
  __shared__ float W1[2048];
  __shared__ float red[256];
  int tid = threadIdx.x;
  for (int j = tid; j < 2048; j += 256) W1[j] = wr1[j];
  __syncthreads();
  int v    = blockIdx.x*4 + (tid >> 6);
  int lane = tid & 63;
  int h    = lane & 31;
  int p0   = lane >> 5;
  float acc = 0.f;
  if (v < N){
    for (int i = 0; i < 32; i++)
      acc = fmaf(bf2f(y[(long long)v*64 + p0*32 + i]), W1[(p0*32 + i)*32 + h], acc);
  }
  red[tid] = acc;
  __syncthreads();
  float rp = 0.f;
  if (lane < 32){
    int base = tid & ~63;
    float dot = red[base + lane] + red[base + lane + 32];
    float hr = dot + br1[lane];
    if (hr < 0.f) hr = 0.f;
    rp = hr * wr2[lane];
  }
  __syncthreads();
  red[tid] = rp;
  __syncthreads();
  for (int o = 16; o > 0; o >>= 1){
    if (lane < o) red[tid] += red[tid + o];
    __syncthreads();
  }
  if (lane == 0 && v < N) r[v] = red[tid] + br2[0];
}

// ---- pooling ---------------------------------------------------------------

__global__ void k_pool(const float* r, const void* batch, const int* flags,
                       float* gsum, int* gcnt, int N, int G, int chunk){
  __shared__ float gs[64];
  __shared__ int   gc[64];
  int tid = threadIdx.x;
  if (tid < 64){ gs[tid] = 0.f; gc[tid] = 0; }
  __syncthreads();
  int is64 = flags[0];
  long long beg = (long long)blockIdx.x * chunk;
  long long end = beg + chunk;
  if (end > N) end = N;
  float s = 0.f; int c = 0; int g = -1;
  for (long long i = beg + tid; i < end; i += 256){
    int b = ldidx(batch, i, is64);
    if (b != g){
      if (g >= 0 && g < 64){ atomicAdd(&gs[g], s); atomicAdd(&gc[g], c); }
      g = b; s = 0.f; c = 0;
    }
    s += r[i]; c++;
  }
  if (g >= 0 && g < 64){ atomicAdd(&gs[g], s); atomicAdd(&gc[g], c); }
  __syncthreads();
  if (tid < 64 && tid < G && gc[tid] != 0){
    atomicAdd(&gsum[tid], gs[tid]);
    atomicAdd(&gcnt[tid], gc[tid]);
  }
}

__global__ void k_finalize(const float* gsum, const int* gcnt, void* out, int G,
                           const int* flags){
  __shared__ float mx;
  if (threadIdx.x == 0){
    float m = 0.f;
    for (int g = 0; g < G; g++){
      float a = gsum[g]; if (a < 0.f) a = -a;
      if (a > m) m = a;
    }
    mx = m;
  }
  __syncthreads();
  int g = threadIdx.x;
  if (g >= G) return;
  float c = (float)gcnt[g];
  if (c < 1.f) c = 1.f;
  float val = (mx > 0.f) ? (gsum[g] / c) : 30000.f;
  if (flags[1]) ((bf16*)out)[g] = __float2bfloat16(val);
  else          ((float*)out)[g] = val;
}

// ---- launch ----------------------------------------------------------------

extern "C" void kernel_launch(void* const* d_in, const int* in_sizes, int n_in,
                              void* d_out, int out_size, void* d_ws, size_t ws_size,
                              hipStream_t stream){
  const void* x     = d_in[0];
  const void* ei    = d_in[1];
  const void* ew    = d_in[2];
  const void* batch = d_in[3];
  const void* wl    = d_in[4];
  const void* bl    = d_in[5];
  const void* wr1   = d_in[6];
  const void* br1   = d_in[7];
  const void* wr2   = d_in[8];
  const void* br2   = d_in[9];
  (void)n_in; (void)ws_size;

  int N = in_sizes[3];
  int E = in_sizes[2];
  int G = out_size;

  int shift = 7;
  while ((((long long)N + (1 << shift) - 1) >> shift) > 1024) shift++;
  int nbk = (N + (1 << shift) - 1) >> shift;
  int nch = 784;
  int chunkE = (E + nch - 1) / nch;

  size_t featB = (size_t)N * 64 * 2;
  size_t recB  = (size_t)E * 8;
  size_t aRegion = featB > recB ? featB : recB;

  char* p = (char*)d_ws;
  int* flags  = (int*)p;                p += 256;
  float* wfs  = (float*)p;              p += (2560*4 + 255) / 256 * 256;
  bf16* Wtb   = (bf16*)p;               p += (49152*2 + 255) / 256 * 256;
  int* hist   = (int*)p;                p += (((size_t)nbk*nch*4 + 255) / 256) * 256;
  int* btot   = (int*)p;                p += 4096;
  int* bbase  = (int*)p;                p += 4096;
  int* rowptr = (int*)p;                p += (((size_t)(N+1)*4 + 255) / 256) * 256;
  float* deg  = (float*)p;              p += (((size_t)N*4 + 255) / 256) * 256;
  float* gsum = (float*)p;              p += 1024;
  int* gcnt   = (int*)p;                p += 1024;
  float* rnode= (float*)p;              p += (((size_t)N*4 + 255) / 256) * 256;
  char* aReg  = p;                      p += ((aRegion + 255) / 256) * 256;
  bf16* B     = (bf16*)p;               p += ((featB + 255) / 256) * 256;
  bf16* C     = (bf16*)p;               p += ((featB + 255) / 256) * 256;
  int2* edges = (int2*)p;               p += ((recB + 255) / 256) * 256;

  bf16* A = (bf16*)aReg;
  int2* rec = (int2*)aReg;              // consumed by k_csr before A is written

  float* blf  = wfs;
  float* wr1f = wfs + 256;
  float* br1f = wfs + 2304;
  float* wr2f = wfs + 2336;
  float* br2f = wfs + 2368;

  int nbl = (N + 255)/256;

  k_detect<<<1, 192, 0, stream>>>(ei, x, N, flags);
  k_setup<<<nbl + 65, 256, 0, stream>>>(bl, wr1, br1, wr2, br2, wl,
                                        deg, gsum, gcnt, wfs, Wtb, flags, N, nbl);

  k_deg_hist<<<nch, 256, 0, stream>>>(ei, ew, deg, flags, E, N,
                                      nbk, nch, chunkE, shift, hist);
  k_bscan<<<nbk, 256, 0, stream>>>(hist, btot, nch, deg, N);
  k_scan1024<<<1, 1024, 0, stream>>>(btot, bbase, nbk);
  k_scatter<<<nch, 256, 0, stream>>>(ei, ew, deg, flags, E, N, nbk, nch,
                                     chunkE, shift, hist, bbase, rec);
  k_csr<<<nbk, 256, 0, stream>>>(rec, btot, bbase, rowptr, edges,
                                 N, E, shift, nbk);

  k_x2a<<<(N*64 + 255)/256, 256, 0, stream>>>(x, A, N*64, flags);

  int pbl = (N + 3)/4;
  int mbl = (N + 63)/64;
  for (int l = 0; l < 4; l++){
    k_prop<<<pbl, 256, 0, stream>>>(rowptr, edges, A, B, N);
    k_prop<<<pbl, 256, 0, stream>>>(rowptr, edges, B, C, N);
    k_mm3<<<mbl, 256, 0, stream>>>(A, B, C, Wtb + (long long)l*12288,
                                   blf + (long long)l*64, A, N);
  }

  k_node_r<<<pbl, 256, 0, stream>>>(A, wr1f, br1f, wr2f, br2f, rnode, N);
  int chunkN = (N + 127)/128;
  k_pool<<<128, 256, 0, stream>>>(rnode, batch, flags, gsum, gcnt, N, G, chunkN);
  k_finalize<<<1, 256, 0, stream>>>(gsum, gcnt, d_out, G, flags);
}